// Round 5
// baseline (137.208 us; speedup 1.0000x reference)
//
#include <hip/hip_runtime.h>

using bf16x8  = __attribute__((ext_vector_type(8))) __bf16;
using f32x4   = __attribute__((ext_vector_type(4))) float;
using short8  = __attribute__((ext_vector_type(8))) short;
using float4v = __attribute__((ext_vector_type(4))) float;
using uint2v  = __attribute__((ext_vector_type(2))) unsigned int;

#if __has_builtin(__builtin_amdgcn_exp2f)
#define EXP2F(x) __builtin_amdgcn_exp2f(x)
#else
#define EXP2F(x) __expf((x) * 0.6931472f)
#endif
#if __has_builtin(__builtin_amdgcn_rcpf)
#define RCPF(x) __builtin_amdgcn_rcpf(x)
#else
#define RCPF(x) (1.f / (x))
#endif

static __device__ __forceinline__ unsigned short bfu(float f) {
    return __builtin_bit_cast(unsigned short, (__bf16)f);
}
static __device__ __forceinline__ unsigned int pkbf(float a, float b) {
    return (unsigned int)bfu(a) | ((unsigned int)bfu(b) << 16);
}
static __device__ __forceinline__ bf16x8 as_bf(short8 s) {
    return __builtin_bit_cast(bf16x8, s);
}
static __device__ __forceinline__ bf16x8 cvt8(float4v lo, float4v hi) {
    union { unsigned int u[4]; bf16x8 v; } r;
    r.u[0] = pkbf(lo[0], lo[1]); r.u[1] = pkbf(lo[2], lo[3]);
    r.u[2] = pkbf(hi[0], hi[1]); r.u[3] = pkbf(hi[2], hi[3]);
    return r.v;
}

// ---- weight prep: fp32 [k][c] -> bf16 [ks][c][32] (k-tiled, lane-coalesced) ----
__global__ void prep_weights(const float* __restrict__ Wq, const float* __restrict__ Wk,
                             const float* __restrict__ Wv, const float* __restrict__ Wo,
                             unsigned short* __restrict__ wq2, unsigned short* __restrict__ wo2) {
    int idx = blockIdx.x * 256 + threadIdx.x;
    if (idx < 384 * 256) {
        int c = idx >> 8, k = idx & 255;
        float v = (c < 128) ? Wq[k * 128 + c]
                : (c < 256) ? Wk[k * 128 + (c - 128)]
                            : Wv[k * 128 + (c - 256)];
        wq2[(k >> 5) * 12288 + (c << 5) + (k & 31)] = bfu(v);
    } else {
        int j = idx - 384 * 256;
        int c = j >> 7, k = j & 127;
        wo2[(k >> 5) * 4096 + (c << 5) + (k & 31)] = bfu(Wo[k * 128 + c]);
    }
}

// LDS (49152 B -> 3 blocks/CU):
//  SQ: Q / attn-out [64 t][256B] (128 bf16), swz byte ^= (t&7)<<4
//  SK: K           [64 t][256B], same swz
//  SV: Vt          [128 cv][128B] (64 t), swz (cv&7)<<4
__global__ __launch_bounds__(256, 3)
void fused_attn(const float* __restrict__ X, const float* __restrict__ STE,
                const float* __restrict__ bq, const float* __restrict__ bk,
                const float* __restrict__ bv, const float* __restrict__ bo,
                const unsigned short* __restrict__ wq2, const unsigned short* __restrict__ wo2,
                float* __restrict__ out) {
    __shared__ __align__(16) char sm[49152];
    constexpr int SQ = 0, SK = 16384, SV = 32768;
    const float SC2 = 0.36067376f;  // 0.25 * log2(e)

    const int tid  = threadIdx.x;
    const int lane = tid & 63;
    const int w    = tid >> 6;
    const int bid  = blockIdx.x;
    const int n    = bid & 255;
    const int b    = bid >> 8;
    const int lr   = lane & 15;
    const int lg   = lane >> 4;
    const int rsw  = (lr & 7) << 4;   // swizzle for rows == lr (mod 16): byte bits 4-6

    const size_t base = (size_t)(b * 16384 + n) * 128;
    const float* xr[4];
    const float* sr[4];
    #pragma unroll
    for (int m = 0; m < 4; ++m) {
        size_t t = m * 16 + lr;
        xr[m] = X   + base + t * 32768;
        sr[m] = STE + base + t * 32768;
    }

    // ---------- GEMM1: QKV = Xc[64][256] @ Wqkv[256][384]; A direct from global ----------
    const int c0 = w * 96;
    f32x4 acc[4][6];
    #pragma unroll
    for (int m = 0; m < 4; ++m)
        #pragma unroll
        for (int i = 0; i < 6; ++i)
            acc[m][i] = f32x4{0.f, 0.f, 0.f, 0.f};

    #pragma unroll
    for (int ks = 0; ks < 8; ++ks) {
        bf16x8 bcur[6];
        #pragma unroll
        for (int i = 0; i < 6; ++i)
            bcur[i] = as_bf(*reinterpret_cast<const short8*>(
                wq2 + (size_t)ks * 12288 + (size_t)(c0 + i * 16 + lr) * 32 + lg * 8));
        bf16x8 a[4];
        #pragma unroll
        for (int m = 0; m < 4; ++m) {
            const float* rp = ((ks < 4) ? xr[m] : sr[m]) + (ks & 3) * 32 + lg * 8;
            float4v lo = *reinterpret_cast<const float4v*>(rp);
            float4v hi = *reinterpret_cast<const float4v*>(rp + 4);
            a[m] = cvt8(lo, hi);
        }
        #pragma unroll
        for (int m = 0; m < 4; ++m)
            #pragma unroll
            for (int i = 0; i < 6; ++i)
                acc[m][i] = __builtin_amdgcn_mfma_f32_16x16x32_bf16(a[m], bcur[i], acc[m][i], 0, 0, 0);
    }

    // epilogue: bias+relu -> Q, K (u16, swizzled) and Vt (transposed b64)
    #pragma unroll
    for (int i = 0; i < 6; ++i) {
        int c = c0 + i * 16 + lr;
        if (c < 256) {
            int qi = c >> 7, cc = c & 127;
            char* rbase = sm + (qi ? SK : SQ);
            float bvv = (qi ? bk : bq)[cc];
            #pragma unroll
            for (int m = 0; m < 4; ++m)
                #pragma unroll
                for (int r = 0; r < 4; ++r) {
                    int t = m * 16 + lg * 4 + r;
                    *reinterpret_cast<unsigned short*>(
                        rbase + (t << 8) + ((cc * 2) ^ ((t & 7) << 4)))
                        = bfu(fmaxf(acc[m][i][r] + bvv, 0.f));
                }
        } else {
            int cv = c - 256;
            float bvv = bv[cv];
            #pragma unroll
            for (int m = 0; m < 4; ++m) {
                uint2v d;
                d[0] = pkbf(fmaxf(acc[m][i][0] + bvv, 0.f), fmaxf(acc[m][i][1] + bvv, 0.f));
                d[1] = pkbf(fmaxf(acc[m][i][2] + bvv, 0.f), fmaxf(acc[m][i][3] + bvv, 0.f));
                *reinterpret_cast<uint2v*>(
                    sm + SV + (cv << 7) + ((m * 32 + lg * 8) ^ ((cv & 7) << 4))) = d;
            }
        }
    }
    __syncthreads();

    // ---------- attention: wave w owns chunks 4w..4w+3 (all wave-local) ----------
    const f32x4 zf = {0.f, 0.f, 0.f, 0.f};
    const short8 z8 = {0, 0, 0, 0, 0, 0, 0, 0};
    short8 ones8;
    #pragma unroll
    for (int h = 0; h < 8; ++h) ones8[h] = (short)0x3F80;  // bf16 1.0

    #pragma unroll 1
    for (int ci = 0; ci < 4; ++ci) {
        const int cb  = (w * 4 + ci) * 8;
        const int cbB = cb * 2;

        // K,Q fragments (h in k-slot lg=0 only)
        bf16x8 kf[4], qf[4];
        #pragma unroll
        for (int j = 0; j < 4; ++j) {
            kf[j] = (lg == 0)
                ? as_bf(*reinterpret_cast<const short8*>(
                      sm + SK + ((j * 16 + lr) << 8) + (cbB ^ rsw)))
                : as_bf(z8);
            qf[j] = (lg == 0)
                ? as_bf(*reinterpret_cast<const short8*>(
                      sm + SQ + ((j * 16 + lr) << 8) + (cbB ^ rsw)))
                : as_bf(z8);
        }
        // V fragments for both k-halves (+ones rows 8,12 for denominator)
        bf16x8 vf[2];
        #pragma unroll
        for (int ks = 0; ks < 2; ++ks) {
            int vr = min(cb + lr, 127);
            vf[ks] = as_bf(*reinterpret_cast<const short8*>(
                sm + SV + (vr << 7) + ((ks * 64 + lg * 16) ^ ((vr & 7) << 4))));
            if (lr == 8 || lr == 12) vf[ks] = as_bf(ones8);
        }

        #pragma unroll
        for (int nt = 0; nt < 4; ++nt) {
            // S^T tiles -> exp2 -> packed bf16 pairs in registers
            // p2[st][q]: rows s = st*16 + lg*4 + {2q, 2q+1}, col t = nt*16 + lr
            unsigned int p2[4][2];
            #pragma unroll
            for (int st = 0; st < 4; ++st) {
                if (st > nt) { p2[st][0] = 0; p2[st][1] = 0; continue; }
                f32x4 sv = __builtin_amdgcn_mfma_f32_16x16x32_bf16(kf[st], qf[nt], zf, 0, 0, 0);
                float p[4];
                #pragma unroll
                for (int r = 0; r < 4; ++r) p[r] = EXP2F(sv[r] * SC2);
                if (st == nt) {
                    #pragma unroll
                    for (int r = 0; r < 4; ++r) p[r] = (lg * 4 + r <= lr) ? p[r] : 0.f;
                }
                p2[st][0] = pkbf(p[0], p[1]);
                p2[st][1] = pkbf(p[2], p[3]);
            }

            // PV: O^T = [V^T; ones] * P ; B-frag via cross-lane shuffle.
            // Dest lane (lr,lg), word q needs P rows s = 32ks + 8lg + {2q,2q+1},
            // col t = nt*16+lr  ->  tile st = 2ks + (lg>>1), source lane
            // srcl = lr + 16*(2*(lg&1) + (q>>1)), word q&1.
            // NOTE: shfl ships the SOURCE lane's expression, so shuffle BOTH
            // candidate tiles and select with MY lg (round-4 bug fix).
            f32x4 o = zf;
            #pragma unroll
            for (int ks = 0; ks < 2; ++ks) {
                if (nt < 2 * ks) continue;
                unsigned int bw[4];
                #pragma unroll
                for (int q = 0; q < 4; ++q) {
                    int srcl = lr + 16 * (2 * (lg & 1) + (q >> 1));
                    unsigned int v0 = __shfl(p2[2 * ks][q & 1], srcl);
                    unsigned int v1 = __shfl(p2[2 * ks + 1][q & 1], srcl);
                    bw[q] = (lg & 2) ? v1 : v0;
                }
                bf16x8 pf = __builtin_bit_cast(bf16x8, bw);
                o = __builtin_amdgcn_mfma_f32_16x16x32_bf16(vf[ks], pf, o, 0, 0, 0);
            }

            // finalize: l from ones rows (8,12) -> lanes lg<2; write attn-out into Q cols
            float l   = __shfl_xor(o[0], 32);
            float inv = RCPF(l);
            if (lg < 2) {
                int t_ = nt * 16 + lr;
                uint2v d;
                d[0] = pkbf(o[0] * inv, o[1] * inv);
                d[1] = pkbf(o[2] * inv, o[3] * inv);
                *reinterpret_cast<uint2v*>(
                    sm + SQ + (t_ << 8) + ((cbB + lg * 8) ^ rsw)) = d;
            }
        }
    }
    __syncthreads();

    // ---------- GEMM2: out = aout[64][128] @ Wo[128][128] + bo, relu ----------
    f32x4 acc2[4][2];
    #pragma unroll
    for (int m = 0; m < 4; ++m)
        #pragma unroll
        for (int i = 0; i < 2; ++i)
            acc2[m][i] = zf;

    #pragma unroll
    for (int ks = 0; ks < 4; ++ks) {
        bf16x8 a2[4];
        #pragma unroll
        for (int m = 0; m < 4; ++m)
            a2[m] = as_bf(*reinterpret_cast<const short8*>(
                sm + SQ + ((m * 16 + lr) << 8) + ((ks * 64 + lg * 16) ^ rsw)));
        bf16x8 b2[2];
        #pragma unroll
        for (int i = 0; i < 2; ++i)
            b2[i] = as_bf(*reinterpret_cast<const short8*>(
                wo2 + (size_t)ks * 4096 + (size_t)((w + 4 * i) * 16 + lr) * 32 + lg * 8));
        #pragma unroll
        for (int m = 0; m < 4; ++m)
            #pragma unroll
            for (int i = 0; i < 2; ++i)
                acc2[m][i] = __builtin_amdgcn_mfma_f32_16x16x32_bf16(a2[m], b2[i], acc2[m][i], 0, 0, 0);
    }

    float* obase = out + base;
    #pragma unroll
    for (int i = 0; i < 2; ++i) {
        int c = (w + 4 * i) * 16 + lr;
        float bias = bo[c];
        #pragma unroll
        for (int m = 0; m < 4; ++m)
            #pragma unroll
            for (int r = 0; r < 4; ++r) {
                int tt = m * 16 + lg * 4 + r;
                obase[(size_t)tt * 32768 + c] = fmaxf(acc2[m][i][r] + bias, 0.f);
            }
    }
}

extern "C" void kernel_launch(void* const* d_in, const int* in_sizes, int n_in,
                              void* d_out, int out_size, void* d_ws, size_t ws_size,
                              hipStream_t stream) {
    const float* X   = (const float*)d_in[0];
    const float* STE = (const float*)d_in[1];
    const float* Wq  = (const float*)d_in[2];
    const float* bq  = (const float*)d_in[3];
    const float* Wk  = (const float*)d_in[4];
    const float* bk  = (const float*)d_in[5];
    const float* Wv  = (const float*)d_in[6];
    const float* bv  = (const float*)d_in[7];
    const float* Wo  = (const float*)d_in[8];
    const float* bo  = (const float*)d_in[9];
    float* out = (float*)d_out;

    unsigned short* wq2 = (unsigned short*)d_ws;      // 384*256 bf16
    unsigned short* wo2 = wq2 + 384 * 256;            // 128*128 bf16

    prep_weights<<<448, 256, 0, stream>>>(Wq, Wk, Wv, Wo, wq2, wo2);
    fused_attn<<<2048, 256, 0, stream>>>(X, STE, bq, bk, bv, bo, wq2, wo2, out);
}

// Round 6
// 83.671 us; speedup vs baseline: 1.6399x; 1.6399x over previous
//
#include <hip/hip_runtime.h>

using bf16x8  = __attribute__((ext_vector_type(8))) __bf16;
using f32x4   = __attribute__((ext_vector_type(4))) float;
using short8  = __attribute__((ext_vector_type(8))) short;
using float4v = __attribute__((ext_vector_type(4))) float;
using uint2v  = __attribute__((ext_vector_type(2))) unsigned int;

#if __has_builtin(__builtin_amdgcn_exp2f)
#define EXP2F(x) __builtin_amdgcn_exp2f(x)
#else
#define EXP2F(x) __expf((x) * 0.6931472f)
#endif
#if __has_builtin(__builtin_amdgcn_rcpf)
#define RCPF(x) __builtin_amdgcn_rcpf(x)
#else
#define RCPF(x) (1.f / (x))
#endif

static __device__ __forceinline__ unsigned short bfu(float f) {
    return __builtin_bit_cast(unsigned short, (__bf16)f);
}
static __device__ __forceinline__ unsigned int pkbf(float a, float b) {
    return (unsigned int)bfu(a) | ((unsigned int)bfu(b) << 16);
}
static __device__ __forceinline__ bf16x8 as_bf(short8 s) {
    return __builtin_bit_cast(bf16x8, s);
}

// ---- weight prep: fp32 [k][c] -> bf16 [ks][c][32] (k-tiled, lane-coalesced) ----
__global__ void prep_weights(const float* __restrict__ Wq, const float* __restrict__ Wk,
                             const float* __restrict__ Wv, const float* __restrict__ Wo,
                             unsigned short* __restrict__ wq2, unsigned short* __restrict__ wo2) {
    int idx = blockIdx.x * 256 + threadIdx.x;
    if (idx < 384 * 256) {
        int c = idx >> 8, k = idx & 255;
        float v = (c < 128) ? Wq[k * 128 + c]
                : (c < 256) ? Wk[k * 128 + (c - 128)]
                            : Wv[k * 128 + (c - 256)];
        wq2[(k >> 5) * 12288 + (c << 5) + (k & 31)] = bfu(v);
    } else {
        int j = idx - 384 * 256;
        int c = j >> 7, k = j & 127;
        wo2[(k >> 5) * 4096 + (c << 5) + (k & 31)] = bfu(Wo[k * 128 + c]);
    }
}

// LDS 49152 B -> 3 blocks/CU, TIME-SHARED:
//  phase 1 (staging+GEMM1): xc [64 t][512B] (256 bf16) at [0..32K), swz byte^=(t&7)<<4
//  phase 2+ : SQ [64 t][256B] at [0..16K), SK at [16K..32K), swz (t&7)<<4
//             SV (V^T) [128 cv][128B] at [32K..48K), swz (cv&7)<<4
__global__ __launch_bounds__(256, 3)
void fused_attn(const float* __restrict__ X, const float* __restrict__ STE,
                const float* __restrict__ bq, const float* __restrict__ bk,
                const float* __restrict__ bv, const float* __restrict__ bo,
                const unsigned short* __restrict__ wq2, const unsigned short* __restrict__ wo2,
                float* __restrict__ out) {
    __shared__ __align__(16) char sm[49152];
    constexpr int SQ = 0, SK = 16384, SV = 32768;
    const float SC2 = 0.36067376f;  // 0.25 * log2(e)

    const int tid  = threadIdx.x;
    const int lane = tid & 63;
    const int w    = tid >> 6;
    const int bid  = blockIdx.x;
    const int n    = bid & 255;
    const int b    = bid >> 8;
    const int lr   = lane & 15;
    const int lg   = lane >> 4;
    const int rsw  = (lr & 7) << 4;   // swizzle (bank bits 4-6) for rows == lr (mod 16)

    const size_t base = (size_t)(b * 16384 + n) * 128;
    const float* xbase = X   + base;
    const float* sbase = STE + base;

    // ---- prefetch first weight k-tile (independent of staging) ----
    const int c0 = w * 96;
    bf16x8 bnxt[6];
    #pragma unroll
    for (int i = 0; i < 6; ++i)
        bnxt[i] = as_bf(*reinterpret_cast<const short8*>(
            wq2 + (size_t)(c0 + i * 16 + lr) * 32 + lg * 8));

    // ---------- stage Xc = [X | STE] as bf16 into xc (coalesced float4/lane) ----------
    #pragma unroll
    for (int it = 0; it < 16; ++it) {
        int t = w + it * 4;
        const float* src = (lane < 32) ? (xbase + (size_t)t * 32768 + lane * 4)
                                       : (sbase + (size_t)t * 32768 + (lane - 32) * 4);
        float4v v = *reinterpret_cast<const float4v*>(src);
        uint2v d;
        d[0] = pkbf(v[0], v[1]);
        d[1] = pkbf(v[2], v[3]);
        *reinterpret_cast<uint2v*>(sm + (t << 9) + ((lane * 8) ^ ((t & 7) << 4))) = d;
    }
    __syncthreads();

    // ---------- GEMM1: QKV = Xc[64][256] @ Wqkv[256][384] ----------
    f32x4 acc[4][6];
    #pragma unroll
    for (int m = 0; m < 4; ++m)
        #pragma unroll
        for (int i = 0; i < 6; ++i)
            acc[m][i] = f32x4{0.f, 0.f, 0.f, 0.f};

    #pragma unroll
    for (int ks = 0; ks < 8; ++ks) {
        bf16x8 bcur[6];
        #pragma unroll
        for (int i = 0; i < 6; ++i) bcur[i] = bnxt[i];
        if (ks < 7) {
            #pragma unroll
            for (int i = 0; i < 6; ++i)
                bnxt[i] = as_bf(*reinterpret_cast<const short8*>(
                    wq2 + (size_t)(ks + 1) * 12288 + (size_t)(c0 + i * 16 + lr) * 32 + lg * 8));
        }
        bf16x8 a[4];
        #pragma unroll
        for (int m = 0; m < 4; ++m)
            a[m] = as_bf(*reinterpret_cast<const short8*>(
                sm + ((m * 16 + lr) << 9) + ((ks * 64 + lg * 16) ^ rsw)));
        #pragma unroll
        for (int m = 0; m < 4; ++m)
            #pragma unroll
            for (int i = 0; i < 6; ++i)
                acc[m][i] = __builtin_amdgcn_mfma_f32_16x16x32_bf16(a[m], bcur[i], acc[m][i], 0, 0, 0);
    }
    __syncthreads();  // all xc reads done; safe to overwrite with Q/K

    // epilogue: bias+relu -> Q,K (u16, swizzled) and V^T (transposed b64)
    #pragma unroll
    for (int i = 0; i < 6; ++i) {
        int c = c0 + i * 16 + lr;
        if (c < 256) {
            int qi = c >> 7, cc = c & 127;
            char* rbase = sm + (qi ? SK : SQ);
            float bvv = (qi ? bk : bq)[cc];
            #pragma unroll
            for (int m = 0; m < 4; ++m)
                #pragma unroll
                for (int r = 0; r < 4; ++r) {
                    int t = m * 16 + lg * 4 + r;
                    *reinterpret_cast<unsigned short*>(
                        rbase + (t << 8) + ((cc * 2) ^ ((t & 7) << 4)))
                        = bfu(fmaxf(acc[m][i][r] + bvv, 0.f));
                }
        } else {
            int cv = c - 256;
            float bvv = bv[cv];
            #pragma unroll
            for (int m = 0; m < 4; ++m) {
                uint2v d;
                d[0] = pkbf(fmaxf(acc[m][i][0] + bvv, 0.f), fmaxf(acc[m][i][1] + bvv, 0.f));
                d[1] = pkbf(fmaxf(acc[m][i][2] + bvv, 0.f), fmaxf(acc[m][i][3] + bvv, 0.f));
                *reinterpret_cast<uint2v*>(
                    sm + SV + (cv << 7) + ((m * 32 + lg * 8) ^ ((cv & 7) << 4))) = d;
            }
        }
    }
    __syncthreads();

    // ---------- attention: wave w owns chunks 4w..4w+3 (all wave-local) ----------
    const f32x4 zf = {0.f, 0.f, 0.f, 0.f};
    const short8 z8 = {0, 0, 0, 0, 0, 0, 0, 0};
    short8 ones8;
    #pragma unroll
    for (int h = 0; h < 8; ++h) ones8[h] = (short)0x3F80;  // bf16 1.0

    #pragma unroll 1
    for (int ci = 0; ci < 4; ++ci) {
        const int cb  = (w * 4 + ci) * 8;
        const int cbB = cb * 2;

        // K,Q fragments (h in k-slot lg=0 only)
        bf16x8 kf[4], qf[4];
        #pragma unroll
        for (int j = 0; j < 4; ++j) {
            kf[j] = (lg == 0)
                ? as_bf(*reinterpret_cast<const short8*>(
                      sm + SK + ((j * 16 + lr) << 8) + (cbB ^ rsw)))
                : as_bf(z8);
            qf[j] = (lg == 0)
                ? as_bf(*reinterpret_cast<const short8*>(
                      sm + SQ + ((j * 16 + lr) << 8) + (cbB ^ rsw)))
                : as_bf(z8);
        }
        // V fragments for both k-halves (+ones rows 8,12 for denominator)
        bf16x8 vf[2];
        #pragma unroll
        for (int ks = 0; ks < 2; ++ks) {
            int vr = min(cb + lr, 127);
            vf[ks] = as_bf(*reinterpret_cast<const short8*>(
                sm + SV + (vr << 7) + ((ks * 64 + lg * 16) ^ ((vr & 7) << 4))));
            if (lr == 8 || lr == 12) vf[ks] = as_bf(ones8);
        }

        #pragma unroll
        for (int nt = 0; nt < 4; ++nt) {
            // S^T tiles -> exp2 -> packed bf16 pairs in registers
            unsigned int p2[4][2];
            #pragma unroll
            for (int st = 0; st < 4; ++st) {
                if (st > nt) { p2[st][0] = 0; p2[st][1] = 0; continue; }
                f32x4 sv = __builtin_amdgcn_mfma_f32_16x16x32_bf16(kf[st], qf[nt], zf, 0, 0, 0);
                float p[4];
                #pragma unroll
                for (int r = 0; r < 4; ++r) p[r] = EXP2F(sv[r] * SC2);
                if (st == nt) {
                    #pragma unroll
                    for (int r = 0; r < 4; ++r) p[r] = (lg * 4 + r <= lr) ? p[r] : 0.f;
                }
                p2[st][0] = pkbf(p[0], p[1]);
                p2[st][1] = pkbf(p[2], p[3]);
            }

            // PV: O^T = [V^T; ones] * P ; B-frag via cross-lane shuffle
            // (shuffle BOTH candidate tiles, select with MY lg — r4 bug fix)
            f32x4 o = zf;
            #pragma unroll
            for (int ks = 0; ks < 2; ++ks) {
                if (nt < 2 * ks) continue;
                unsigned int bw[4];
                #pragma unroll
                for (int q = 0; q < 4; ++q) {
                    int srcl = lr + 16 * (2 * (lg & 1) + (q >> 1));
                    unsigned int v0 = __shfl(p2[2 * ks][q & 1], srcl);
                    unsigned int v1 = __shfl(p2[2 * ks + 1][q & 1], srcl);
                    bw[q] = (lg & 2) ? v1 : v0;
                }
                bf16x8 pf = __builtin_bit_cast(bf16x8, bw);
                o = __builtin_amdgcn_mfma_f32_16x16x32_bf16(vf[ks], pf, o, 0, 0, 0);
            }

            // finalize: l from ones rows -> lanes lg<2; write attn-out into Q cols
            float l   = __shfl_xor(o[0], 32);
            float inv = RCPF(l);
            if (lg < 2) {
                int t_ = nt * 16 + lr;
                uint2v d;
                d[0] = pkbf(o[0] * inv, o[1] * inv);
                d[1] = pkbf(o[2] * inv, o[3] * inv);
                *reinterpret_cast<uint2v*>(
                    sm + SQ + (t_ << 8) + ((cbB + lg * 8) ^ rsw)) = d;
            }
        }
    }
    __syncthreads();

    // ---------- GEMM2: out = aout[64][128] @ Wo[128][128] + bo, relu ----------
    f32x4 acc2[4][2];
    #pragma unroll
    for (int m = 0; m < 4; ++m)
        #pragma unroll
        for (int i = 0; i < 2; ++i)
            acc2[m][i] = zf;

    #pragma unroll
    for (int ks = 0; ks < 4; ++ks) {
        bf16x8 a2[4];
        #pragma unroll
        for (int m = 0; m < 4; ++m)
            a2[m] = as_bf(*reinterpret_cast<const short8*>(
                sm + SQ + ((m * 16 + lr) << 8) + ((ks * 64 + lg * 16) ^ rsw)));
        bf16x8 b2[2];
        #pragma unroll
        for (int i = 0; i < 2; ++i)
            b2[i] = as_bf(*reinterpret_cast<const short8*>(
                wo2 + (size_t)ks * 4096 + (size_t)((w + 4 * i) * 16 + lr) * 32 + lg * 8));
        #pragma unroll
        for (int m = 0; m < 4; ++m)
            #pragma unroll
            for (int i = 0; i < 2; ++i)
                acc2[m][i] = __builtin_amdgcn_mfma_f32_16x16x32_bf16(a2[m], b2[i], acc2[m][i], 0, 0, 0);
    }

    float* obase = out + base;
    #pragma unroll
    for (int i = 0; i < 2; ++i) {
        int c = (w + 4 * i) * 16 + lr;
        float bias = bo[c];
        #pragma unroll
        for (int m = 0; m < 4; ++m)
            #pragma unroll
            for (int r = 0; r < 4; ++r) {
                int tt = m * 16 + lg * 4 + r;
                obase[(size_t)tt * 32768 + c] = fmaxf(acc2[m][i][r] + bias, 0.f);
            }
    }
}

extern "C" void kernel_launch(void* const* d_in, const int* in_sizes, int n_in,
                              void* d_out, int out_size, void* d_ws, size_t ws_size,
                              hipStream_t stream) {
    const float* X   = (const float*)d_in[0];
    const float* STE = (const float*)d_in[1];
    const float* Wq  = (const float*)d_in[2];
    const float* bq  = (const float*)d_in[3];
    const float* Wk  = (const float*)d_in[4];
    const float* bk  = (const float*)d_in[5];
    const float* Wv  = (const float*)d_in[6];
    const float* bv  = (const float*)d_in[7];
    const float* Wo  = (const float*)d_in[8];
    const float* bo  = (const float*)d_in[9];
    float* out = (float*)d_out;

    unsigned short* wq2 = (unsigned short*)d_ws;      // 384*256 bf16
    unsigned short* wo2 = wq2 + 384 * 256;            // 128*128 bf16

    prep_weights<<<448, 256, 0, stream>>>(Wq, Wk, Wv, Wo, wq2, wo2);
    fused_attn<<<2048, 256, 0, stream>>>(X, STE, bq, bk, bv, bo, wq2, wo2, out);
}